// Round 1
// baseline (249.734 us; speedup 1.0000x reference)
//
#include <hip/hip_runtime.h>
#include <stdint.h>

#define NB 16
#define NQ 100
#define QP 112   // Q padded to 7*16
#define NG 16384
#define NT 50
#define TP 64    // T padded to 4*16
#define NL 21
#define GW 512   // NG/32 words per mask row

// ws layout (bytes)
#define OFF_BITS  0u
#define SZ_BITS   (NB*TP*GW*4u)            // 2,097,152
#define OFF_MSUM  (OFF_BITS + SZ_BITS)     // 2,097,152
#define SZ_MSUM   (NB*TP*4u)               // 4,096
#define OFF_SSP   (OFF_MSUM + SZ_MSUM)     // 2,101,248
#define SZ_SSP    (NB*QP*4u)               // 7,168
#define OFF_SSG   (OFF_SSP + SZ_SSP)
#define OFF_DOTM  (OFF_SSG + SZ_SSP)
#define SZ_DOT    (NB*QP*TP*4u)            // 458,752
#define OFF_DOTS  (OFF_DOTM + SZ_DOT)
#define ZERO_OFF  OFF_SSP
#define ZERO_SZ   (SZ_SSP*2u + SZ_DOT*2u)  // 931,840

typedef __bf16 bf16x8 __attribute__((ext_vector_type(8)));
typedef float f32x4 __attribute__((ext_vector_type(4)));
union Frag { uint32_t u[4]; bf16x8 v; };

__device__ __forceinline__ uint32_t pack_bf16(float a, float b) {
  uint32_t ua = __float_as_uint(a), ub = __float_as_uint(b);
  ua = (ua + 0x7FFFu + ((ua >> 16) & 1u)) >> 16;
  ub = (ub + 0x7FFFu + ((ub >> 16) & 1u)) & 0xFFFF0000u;
  return ua | ub;
}

// ---------------- kernel 1: pack binary mask to bits + row popcount sums ----
__global__ __launch_bounds__(256) void pack_kernel(
    const float* __restrict__ mask, uint32_t* __restrict__ bits,
    float* __restrict__ msum) {
  int blk = blockIdx.x;
  int b = blk >> 6, t = blk & 63;
  int tid = threadIdx.x;
  int lane = tid & 63, wv = tid >> 6;
  uint32_t* wrow = bits + (size_t)(b*TP + t) * GW;
  if (t < NT) {
    const float* src = mask + (size_t)(b*NT + t) * NG;
    __shared__ int partial[4];
    int cnt = 0;
    int wbase = wv * 4096;
    for (int it = 0; it < 64; ++it) {
      int gb = wbase + it * 64;
      float v = src[gb + lane];
      unsigned long long bal = __ballot(v > 0.5f);
      if (lane == 0) wrow[gb >> 5] = (uint32_t)bal;
      if (lane == 1) wrow[(gb >> 5) + 1] = (uint32_t)(bal >> 32);
      cnt += (int)__popcll(bal);
    }
    if (lane == 0) partial[wv] = cnt;
    __syncthreads();
    if (tid == 0)
      msum[b*TP + t] = (float)(partial[0] + partial[1] + partial[2] + partial[3]);
  } else {
    for (int i = tid; i < GW; i += 256) wrow[i] = 0u;
    if (tid == 0) msum[b*TP + t] = 0.f;
  }
}

// ---------------- kernel 2: dual GEMM (m·maskT, sigmoid(m)·maskT) + row sums
__global__ __launch_bounds__(448) void main_kernel(
    const float* __restrict__ m, const uint32_t* __restrict__ bits,
    float* __restrict__ ssp, float* __restrict__ ssg,
    float* __restrict__ dotm, float* __restrict__ dotsg) {
  int b = blockIdx.x >> 4;
  int chunk = blockIdx.x & 15;        // 16 chunks of 1024 over G
  int tid = threadIdx.x;
  int wv = tid >> 6, lane = tid & 63;
  int row16 = lane & 15, lg = lane >> 4;

  __shared__ uint32_t lbits[TP][33];  // +1 pad word -> conflict-free column reads
  for (int i = tid; i < TP * 32; i += 448) {
    int t = i >> 5, k = i & 31;
    lbits[t][k] = bits[(size_t)(b*TP + t) * GW + chunk*32 + k];
  }
  __syncthreads();

  int q0 = wv * 16;
  int qrow = q0 + row16; if (qrow > NQ - 1) qrow = NQ - 1;  // clamp pad rows
  const float* arow = m + (size_t)(b*NQ + qrow) * NG + chunk*1024 + lg*8;

  f32x4 accm[4], accs[4];
#pragma unroll
  for (int nt = 0; nt < 4; ++nt) {
    accm[nt] = (f32x4)(0.f);
    accs[nt] = (f32x4)(0.f);
  }
  float sspacc = 0.f, ssgacc = 0.f;

  for (int ks = 0; ks < 32; ++ks) {
    const float4* p = (const float4*)(arow + ks*32);
    float4 v0 = p[0], v1 = p[1];
    float av[8] = {v0.x, v0.y, v0.z, v0.w, v1.x, v1.y, v1.z, v1.w};
    Frag mf, sf;
#pragma unroll
    for (int j = 0; j < 8; j += 2) {
      float x0 = av[j], x1 = av[j+1];
      float e0 = __expf(-fabsf(x0)), e1 = __expf(-fabsf(x1));
      float r0 = __builtin_amdgcn_rcpf(1.f + e0);
      float r1 = __builtin_amdgcn_rcpf(1.f + e1);
      float sg0 = (x0 >= 0.f) ? r0 : 1.f - r0;   // sigmoid
      float sg1 = (x1 >= 0.f) ? r1 : 1.f - r1;
      float sp0 = fmaxf(x0, 0.f) + __logf(1.f + e0);  // softplus
      float sp1 = fmaxf(x1, 0.f) + __logf(1.f + e1);
      sspacc += sp0 + sp1;
      ssgacc += sg0 + sg1;
      mf.u[j >> 1] = pack_bf16(x0, x1);
      sf.u[j >> 1] = pack_bf16(sg0, sg1);
    }
#pragma unroll
    for (int nt = 0; nt < 4; ++nt) {
      int t = nt*16 + row16;
      uint32_t w = lbits[t][ks];
      uint32_t byte = (w >> (lg * 8)) & 0xFFu;
      Frag bf;
#pragma unroll
      for (int j = 0; j < 4; ++j) {
        uint32_t lo = (byte >> (2*j)) & 1u, hi = (byte >> (2*j + 1)) & 1u;
        bf.u[j] = (lo ? 0x3F80u : 0u) | (hi ? 0x3F800000u : 0u);
      }
      accm[nt] = __builtin_amdgcn_mfma_f32_16x16x32_bf16(mf.v, bf.v, accm[nt], 0, 0, 0);
      accs[nt] = __builtin_amdgcn_mfma_f32_16x16x32_bf16(sf.v, bf.v, accs[nt], 0, 0, 0);
    }
  }

  // row sums: lanes {l, l^16, l^32, l^48} share a q-row
  sspacc += __shfl_xor(sspacc, 16); sspacc += __shfl_xor(sspacc, 32);
  ssgacc += __shfl_xor(ssgacc, 16); ssgacc += __shfl_xor(ssgacc, 32);
  if (lg == 0) {
    atomicAdd(&ssp[b*QP + q0 + row16], sspacc);
    atomicAdd(&ssg[b*QP + q0 + row16], ssgacc);
  }
  // C/D layout: col = lane&15 (t), row = (lane>>4)*4 + r (q offset)
#pragma unroll
  for (int nt = 0; nt < 4; ++nt) {
    int t = nt*16 + row16;
#pragma unroll
    for (int r = 0; r < 4; ++r) {
      int qq = q0 + lg*4 + r;
      atomicAdd(&dotm[(size_t)(b*QP + qq)*TP + t], accm[nt][r]);
      atomicAdd(&dotsg[(size_t)(b*QP + qq)*TP + t], accs[nt][r]);
    }
  }
}

// ---------------- kernel 3: class softmax + assemble output ----------------
__global__ __launch_bounds__(64) void finalize_kernel(
    const float* __restrict__ cls, const int* __restrict__ labels,
    const float* __restrict__ msum, const float* __restrict__ ssp,
    const float* __restrict__ ssg, const float* __restrict__ dotm,
    const float* __restrict__ dotsg, float* __restrict__ out) {
  int blk = blockIdx.x;
  int b = blk / NQ, q = blk % NQ;
  int lane = threadIdx.x;
  const float* lgt = cls + (size_t)(b*NQ + q) * NL;
  float v = (lane < NL) ? lgt[lane] : -1e30f;
  float mx = v;
  for (int s = 32; s; s >>= 1) mx = fmaxf(mx, __shfl_xor(mx, s));
  float e = (lane < NL) ? __expf(v - mx) : 0.f;
  float se = e;
  for (int s = 32; s; s >>= 1) se += __shfl_xor(se, s);

  if (lane < NT) {
    int lbl = labels[b*NT + lane];
    float p = __expf(lgt[lbl] - mx) / se;           // softmax prob at label
    float s1 = ssp[b*QP + q];
    float sg = ssg[b*QP + q];
    float dm = dotm[(size_t)(b*QP + q)*TP + lane];
    float ds = dotsg[(size_t)(b*QP + q)*TP + lane];
    float cmask = (s1 - dm) * (1.f / (float)NG);
    float cdice = 1.f - (2.f*ds + 1.f) / (sg + msum[b*TP + lane] + 1.f);
    out[(size_t)(b*NQ + q)*NT + lane] = cmask - p + cdice;
  }
}

extern "C" void kernel_launch(void* const* d_in, const int* in_sizes, int n_in,
                              void* d_out, int out_size, void* d_ws, size_t ws_size,
                              hipStream_t stream) {
  const float* mq = (const float*)d_in[0];   // [16,100,16384]
  const float* cq = (const float*)d_in[1];   // [16,100,21]
  const float* ml = (const float*)d_in[2];   // [16,50,16384]
  const int*   cl = (const int*)d_in[3];     // [16,50]
  char* ws = (char*)d_ws;
  uint32_t* bits = (uint32_t*)(ws + OFF_BITS);
  float* msum = (float*)(ws + OFF_MSUM);
  float* ssp  = (float*)(ws + OFF_SSP);
  float* ssg  = (float*)(ws + OFF_SSG);
  float* dotm = (float*)(ws + OFF_DOTM);
  float* dotsg= (float*)(ws + OFF_DOTS);

  hipMemsetAsync(ws + ZERO_OFF, 0, ZERO_SZ, stream);
  pack_kernel<<<NB*TP, 256, 0, stream>>>(ml, bits, msum);
  main_kernel<<<NB*16, 448, 0, stream>>>(mq, bits, ssp, ssg, dotm, dotsg);
  finalize_kernel<<<NB*NQ, 64, 0, stream>>>(cq, cl, msum, ssp, ssg, dotm, dotsg, (float*)d_out);
}

// Round 3
// 226.238 us; speedup vs baseline: 1.1039x; 1.1039x over previous
//
#include <hip/hip_runtime.h>
#include <stdint.h>

#define NB 16
#define NQ 100
#define QP 112   // Q padded to 7*16
#define NG 16384
#define NT 50
#define TP 64    // T padded to 4*16
#define NL 21
#define GW 512   // NG/32 words per mask row

typedef __bf16 bf16x8 __attribute__((ext_vector_type(8)));
typedef float f32x4 __attribute__((ext_vector_type(4)));
union Frag { uint32_t u[4]; bf16x8 v; };

__device__ __forceinline__ uint32_t pack_bf16(float a, float b) {
  uint32_t ua = __float_as_uint(a), ub = __float_as_uint(b);
  ua = (ua + 0x7FFFu + ((ua >> 16) & 1u)) >> 16;
  ub = (ub + 0x7FFFu + ((ub >> 16) & 1u)) & 0xFFFF0000u;
  return ua | ub;
}

// ============================================================================
// FAST PATH (v2): Bp = bf16 mask pre-swizzled into MFMA fragment order
//   Bp[b][ksg][t][32 bf16], ksg in [0,512) (K-slab of 32), t in [0,64)
//   t=50..62 zero pad, t=63 all-ones (gives free Sum(sigmoid), Sum(m) columns)
// ============================================================================
#define SZ_BP     ((size_t)NB*512*64*32*2)     // 33,554,432
#define OFF_MSUM2 (SZ_BP)
#define OFF_SSP2  (OFF_MSUM2 + NB*TP*4)        // +4096
#define OFF_DOTM2 (OFF_SSP2 + NB*QP*4)         // +7168
#define OFF_DOTS2 (OFF_DOTM2 + (size_t)NB*QP*TP*4)
#define NEED_V2   (OFF_DOTS2 + (size_t)NB*QP*TP*4)   // 34,483,200
#define ZERO2_OFF OFF_MSUM2
#define ZERO2_SZ  (NEED_V2 - OFF_MSUM2)        // 928,768

// ---- pack: mask f32 -> swizzled bf16 + per-t sums. grid 16*64*4, 64 thr ----
__global__ __launch_bounds__(64) void pack_v2(
    const float* __restrict__ mask, uint32_t* __restrict__ bp,
    float* __restrict__ msum) {
  int blk = blockIdx.x;
  int qtr = blk & 3, t = (blk >> 2) & 63, b = blk >> 8;
  int lane = threadIdx.x;
  uint32_t* dst = bp + (size_t)b * (512*64*16);   // u32 units per batch
  if (t < NT) {
    const float* src = mask + ((size_t)(b*NT + t)) * NG + qtr*4096;
    float cnt = 0.f;
#pragma unroll 4
    for (int it = 0; it < 16; ++it) {
      int g = it*256 + lane*4;
      float4 v = *(const float4*)(src + g);
      cnt += v.x + v.y + v.z + v.w;
      int gg = qtr*4096 + g;
      uint32_t* w = dst + ((size_t)(gg >> 5) * 64 + t) * 16 + ((gg & 31) >> 1);
      uint2 pk; pk.x = pack_bf16(v.x, v.y); pk.y = pack_bf16(v.z, v.w);
      *(uint2*)w = pk;
    }
    cnt += __shfl_xor(cnt, 1);  cnt += __shfl_xor(cnt, 2);
    cnt += __shfl_xor(cnt, 4);  cnt += __shfl_xor(cnt, 8);
    cnt += __shfl_xor(cnt, 16); cnt += __shfl_xor(cnt, 32);
    if (lane == 0) atomicAdd(&msum[b*TP + t], cnt);
  } else {
    uint32_t val = (t == 63) ? 0x3F803F80u : 0u;
    for (int it = 0; it < 16; ++it) {
      int gg = qtr*4096 + it*256 + lane*4;
      uint32_t* w = dst + ((size_t)(gg >> 5) * 64 + t) * 16 + ((gg & 31) >> 1);
      uint2 pk; pk.x = val; pk.y = val;
      *(uint2*)w = pk;
    }
  }
}

// ---- main: dual GEMM via MFMA, A converted in flight. 1-wave blocks. ------
__global__ __launch_bounds__(64) void main_v2(
    const float* __restrict__ m, const char* __restrict__ bp,
    float* __restrict__ ssp, float* __restrict__ dotm,
    float* __restrict__ dotsg) {
  int blk = blockIdx.x;
  int chunk = blk & 31;             // 32 chunks of 512 over G
  int qt = (blk >> 5) % 7;
  int b = blk / 224;
  int lane = threadIdx.x;
  int row16 = lane & 15, lg = lane >> 4;
  int q0 = qt * 16;
  int qrow = q0 + row16; if (qrow > NQ-1) qrow = NQ-1;
  const float* arow = m + (size_t)(b*NQ + qrow)*NG + chunk*512 + lg*8;
  const char* bbase = bp + (size_t)b*2097152 + (size_t)chunk*65536
                         + (row16*32 + lg*8)*2;

  f32x4 accm[4], accs[4];
#pragma unroll
  for (int nt = 0; nt < 4; ++nt) { accm[nt] = (f32x4)(0.f); accs[nt] = (f32x4)(0.f); }
  float sl = 0.f;  // sum of log2(1+e^-x)

#pragma unroll 2
  for (int ks = 0; ks < 16; ++ks) {
    const float4* p = (const float4*)(arow + ks*32);
    float4 v0 = p[0], v1 = p[1];
    float av[8] = {v0.x, v0.y, v0.z, v0.w, v1.x, v1.y, v1.z, v1.w};
    Frag mf, sf;
#pragma unroll
    for (int j = 0; j < 8; j += 2) {
      float x0 = av[j], x1 = av[j+1];
      float e0 = __builtin_amdgcn_exp2f(x0 * -1.442695041f);
      float e1 = __builtin_amdgcn_exp2f(x1 * -1.442695041f);
      float u0 = 1.f + e0, u1 = 1.f + e1;
      float r0 = __builtin_amdgcn_rcpf(u0), r1 = __builtin_amdgcn_rcpf(u1);
      sl += __builtin_amdgcn_logf(u0) + __builtin_amdgcn_logf(u1);
      mf.u[j >> 1] = pack_bf16(x0, x1);
      sf.u[j >> 1] = pack_bf16(r0, r1);
    }
    const char* bk = bbase + ks*4096;
#pragma unroll
    for (int nt = 0; nt < 4; ++nt) {
      bf16x8 bfrag = *(const bf16x8*)(bk + nt*1024);
      accm[nt] = __builtin_amdgcn_mfma_f32_16x16x32_bf16(mf.v, bfrag, accm[nt], 0, 0, 0);
      accs[nt] = __builtin_amdgcn_mfma_f32_16x16x32_bf16(sf.v, bfrag, accs[nt], 0, 0, 0);
    }
  }

  // softplus-log row sums: lanes {l, l^16, l^32, l^48} share a q-row
  sl += __shfl_xor(sl, 16); sl += __shfl_xor(sl, 32);
  if (lg == 0) atomicAdd(&ssp[b*QP + q0 + row16], sl);

  // C/D layout: col = lane&15 (t), row = (lane>>4)*4 + r (q offset)
#pragma unroll
  for (int nt = 0; nt < 4; ++nt) {
    int t = nt*16 + row16;
#pragma unroll
    for (int r = 0; r < 4; ++r) {
      int qq = q0 + lg*4 + r;
      atomicAdd(&dotm [(size_t)(b*QP + qq)*TP + t], accm[nt][r]);
      atomicAdd(&dotsg[(size_t)(b*QP + qq)*TP + t], accs[nt][r]);
    }
  }
}

// ---- finalize: class softmax + assemble ----
__global__ __launch_bounds__(64) void finalize_v2(
    const float* __restrict__ cls, const int* __restrict__ labels,
    const float* __restrict__ msum, const float* __restrict__ ssp,
    const float* __restrict__ dotm, const float* __restrict__ dotsg,
    float* __restrict__ out) {
  int blk = blockIdx.x;
  int b = blk / NQ, q = blk % NQ;
  int lane = threadIdx.x;
  const float* lgt = cls + (size_t)(b*NQ + q) * NL;
  float v = (lane < NL) ? lgt[lane] : -1e30f;
  float mx = v;
  for (int s = 32; s; s >>= 1) mx = fmaxf(mx, __shfl_xor(mx, s));
  float e = (lane < NL) ? __expf(v - mx) : 0.f;
  float se = e;
  for (int s = 32; s; s >>= 1) se += __shfl_xor(se, s);

  if (lane < NT) {
    int lbl = labels[b*NT + lane];
    float p = __expf(lgt[lbl] - mx) / se;
    size_t base = (size_t)(b*QP + q) * TP;
    float s1 = dotm[base + 63] + 0.69314718056f * ssp[b*QP + q];
    float sg = dotsg[base + 63];
    float dm = dotm[base + lane];
    float ds = dotsg[base + lane];
    float cmask = (s1 - dm) * (1.f / (float)NG);
    float cdice = 1.f - (2.f*ds + 1.f) / (sg + msum[b*TP + lane] + 1.f);
    out[(size_t)(b*NQ + q)*NT + lane] = cmask - p + cdice;
  }
}

// ============================================================================
// FALLBACK PATH (v1, proven in R0) — used only if ws_size < NEED_V2
// ============================================================================
#define OFF1_BITS  0u
#define SZ1_BITS   (NB*TP*GW*4u)
#define OFF1_MSUM  (OFF1_BITS + SZ1_BITS)
#define SZ1_MSUM   (NB*TP*4u)
#define OFF1_SSP   (OFF1_MSUM + SZ1_MSUM)
#define SZ1_SSP    (NB*QP*4u)
#define OFF1_SSG   (OFF1_SSP + SZ1_SSP)
#define OFF1_DOTM  (OFF1_SSG + SZ1_SSP)
#define SZ1_DOT    (NB*QP*TP*4u)
#define OFF1_DOTS  (OFF1_DOTM + SZ1_DOT)
#define ZERO1_OFF  OFF1_SSP
#define ZERO1_SZ   (SZ1_SSP*2u + SZ1_DOT*2u)

__global__ __launch_bounds__(256) void pack_v1(
    const float* __restrict__ mask, uint32_t* __restrict__ bits,
    float* __restrict__ msum) {
  int blk = blockIdx.x;
  int b = blk >> 6, t = blk & 63;
  int tid = threadIdx.x;
  int lane = tid & 63, wv = tid >> 6;
  uint32_t* wrow = bits + (size_t)(b*TP + t) * GW;
  if (t < NT) {
    const float* src = mask + (size_t)(b*NT + t) * NG;
    __shared__ int partial[4];
    int cnt = 0;
    int wbase = wv * 4096;
    for (int it = 0; it < 64; ++it) {
      int gb = wbase + it * 64;
      float v = src[gb + lane];
      unsigned long long bal = __ballot(v > 0.5f);
      if (lane == 0) wrow[gb >> 5] = (uint32_t)bal;
      if (lane == 1) wrow[(gb >> 5) + 1] = (uint32_t)(bal >> 32);
      cnt += (int)__popcll(bal);
    }
    if (lane == 0) partial[wv] = cnt;
    __syncthreads();
    if (tid == 0)
      msum[b*TP + t] = (float)(partial[0] + partial[1] + partial[2] + partial[3]);
  } else {
    for (int i = tid; i < GW; i += 256) wrow[i] = 0u;
    if (tid == 0) msum[b*TP + t] = 0.f;
  }
}

__global__ __launch_bounds__(448) void main_v1(
    const float* __restrict__ m, const uint32_t* __restrict__ bits,
    float* __restrict__ ssp, float* __restrict__ ssg,
    float* __restrict__ dotm, float* __restrict__ dotsg) {
  int b = blockIdx.x >> 4;
  int chunk = blockIdx.x & 15;
  int tid = threadIdx.x;
  int wv = tid >> 6, lane = tid & 63;
  int row16 = lane & 15, lg = lane >> 4;

  __shared__ uint32_t lbits[TP][33];
  for (int i = tid; i < TP * 32; i += 448) {
    int t = i >> 5, k = i & 31;
    lbits[t][k] = bits[(size_t)(b*TP + t) * GW + chunk*32 + k];
  }
  __syncthreads();

  int q0 = wv * 16;
  int qrow = q0 + row16; if (qrow > NQ - 1) qrow = NQ - 1;
  const float* arow = m + (size_t)(b*NQ + qrow) * NG + chunk*1024 + lg*8;

  f32x4 accm[4], accs[4];
#pragma unroll
  for (int nt = 0; nt < 4; ++nt) { accm[nt] = (f32x4)(0.f); accs[nt] = (f32x4)(0.f); }
  float sspacc = 0.f, ssgacc = 0.f;

  for (int ks = 0; ks < 32; ++ks) {
    const float4* p = (const float4*)(arow + ks*32);
    float4 v0 = p[0], v1 = p[1];
    float av[8] = {v0.x, v0.y, v0.z, v0.w, v1.x, v1.y, v1.z, v1.w};
    Frag mf, sf;
#pragma unroll
    for (int j = 0; j < 8; j += 2) {
      float x0 = av[j], x1 = av[j+1];
      float e0 = __expf(-fabsf(x0)), e1 = __expf(-fabsf(x1));
      float r0 = __builtin_amdgcn_rcpf(1.f + e0);
      float r1 = __builtin_amdgcn_rcpf(1.f + e1);
      float sg0 = (x0 >= 0.f) ? r0 : 1.f - r0;
      float sg1 = (x1 >= 0.f) ? r1 : 1.f - r1;
      float sp0 = fmaxf(x0, 0.f) + __logf(1.f + e0);
      float sp1 = fmaxf(x1, 0.f) + __logf(1.f + e1);
      sspacc += sp0 + sp1;
      ssgacc += sg0 + sg1;
      mf.u[j >> 1] = pack_bf16(x0, x1);
      sf.u[j >> 1] = pack_bf16(sg0, sg1);
    }
#pragma unroll
    for (int nt = 0; nt < 4; ++nt) {
      int t = nt*16 + row16;
      uint32_t w = lbits[t][ks];
      uint32_t byte = (w >> (lg * 8)) & 0xFFu;
      Frag bf;
#pragma unroll
      for (int j = 0; j < 4; ++j) {
        uint32_t lo = (byte >> (2*j)) & 1u, hi = (byte >> (2*j + 1)) & 1u;
        bf.u[j] = (lo ? 0x3F80u : 0u) | (hi ? 0x3F800000u : 0u);
      }
      accm[nt] = __builtin_amdgcn_mfma_f32_16x16x32_bf16(mf.v, bf.v, accm[nt], 0, 0, 0);
      accs[nt] = __builtin_amdgcn_mfma_f32_16x16x32_bf16(sf.v, bf.v, accs[nt], 0, 0, 0);
    }
  }

  sspacc += __shfl_xor(sspacc, 16); sspacc += __shfl_xor(sspacc, 32);
  ssgacc += __shfl_xor(ssgacc, 16); ssgacc += __shfl_xor(ssgacc, 32);
  if (lg == 0) {
    atomicAdd(&ssp[b*QP + q0 + row16], sspacc);
    atomicAdd(&ssg[b*QP + q0 + row16], ssgacc);
  }
#pragma unroll
  for (int nt = 0; nt < 4; ++nt) {
    int t = nt*16 + row16;
#pragma unroll
    for (int r = 0; r < 4; ++r) {
      int qq = q0 + lg*4 + r;
      atomicAdd(&dotm[(size_t)(b*QP + qq)*TP + t], accm[nt][r]);
      atomicAdd(&dotsg[(size_t)(b*QP + qq)*TP + t], accs[nt][r]);
    }
  }
}

__global__ __launch_bounds__(64) void finalize_v1(
    const float* __restrict__ cls, const int* __restrict__ labels,
    const float* __restrict__ msum, const float* __restrict__ ssp,
    const float* __restrict__ ssg, const float* __restrict__ dotm,
    const float* __restrict__ dotsg, float* __restrict__ out) {
  int blk = blockIdx.x;
  int b = blk / NQ, q = blk % NQ;
  int lane = threadIdx.x;
  const float* lgt = cls + (size_t)(b*NQ + q) * NL;
  float v = (lane < NL) ? lgt[lane] : -1e30f;
  float mx = v;
  for (int s = 32; s; s >>= 1) mx = fmaxf(mx, __shfl_xor(mx, s));
  float e = (lane < NL) ? __expf(v - mx) : 0.f;
  float se = e;
  for (int s = 32; s; s >>= 1) se += __shfl_xor(se, s);

  if (lane < NT) {
    int lbl = labels[b*NT + lane];
    float p = __expf(lgt[lbl] - mx) / se;
    float s1 = ssp[b*QP + q];
    float sg = ssg[b*QP + q];
    float dm = dotm[(size_t)(b*QP + q)*TP + lane];
    float ds = dotsg[(size_t)(b*QP + q)*TP + lane];
    float cmask = (s1 - dm) * (1.f / (float)NG);
    float cdice = 1.f - (2.f*ds + 1.f) / (sg + msum[b*TP + lane] + 1.f);
    out[(size_t)(b*NQ + q)*NT + lane] = cmask - p + cdice;
  }
}

// ============================================================================
extern "C" void kernel_launch(void* const* d_in, const int* in_sizes, int n_in,
                              void* d_out, int out_size, void* d_ws, size_t ws_size,
                              hipStream_t stream) {
  const float* mq = (const float*)d_in[0];   // [16,100,16384]
  const float* cq = (const float*)d_in[1];   // [16,100,21]
  const float* ml = (const float*)d_in[2];   // [16,50,16384]
  const int*   cl = (const int*)d_in[3];     // [16,50]
  char* ws = (char*)d_ws;

  if (ws_size >= NEED_V2) {
    uint32_t* bp  = (uint32_t*)(ws);
    float* msum = (float*)(ws + OFF_MSUM2);
    float* ssp  = (float*)(ws + OFF_SSP2);
    float* dotm = (float*)(ws + OFF_DOTM2);
    float* dotsg= (float*)(ws + OFF_DOTS2);
    hipMemsetAsync(ws + ZERO2_OFF, 0, ZERO2_SZ, stream);
    pack_v2<<<NB*64*4, 64, 0, stream>>>(ml, bp, msum);
    main_v2<<<NB*7*32, 64, 0, stream>>>(mq, (const char*)bp, ssp, dotm, dotsg);
    finalize_v2<<<NB*NQ, 64, 0, stream>>>(cq, cl, msum, ssp, dotm, dotsg, (float*)d_out);
  } else {
    uint32_t* bits = (uint32_t*)(ws + OFF1_BITS);
    float* msum = (float*)(ws + OFF1_MSUM);
    float* ssp  = (float*)(ws + OFF1_SSP);
    float* ssg  = (float*)(ws + OFF1_SSG);
    float* dotm = (float*)(ws + OFF1_DOTM);
    float* dotsg= (float*)(ws + OFF1_DOTS);
    hipMemsetAsync(ws + ZERO1_OFF, 0, ZERO1_SZ, stream);
    pack_v1<<<NB*TP, 256, 0, stream>>>(ml, bits, msum);
    main_v1<<<NB*16, 448, 0, stream>>>(mq, bits, ssp, ssg, dotm, dotsg);
    finalize_v1<<<NB*NQ, 64, 0, stream>>>(cq, cl, msum, ssp, ssg, dotm, dotsg, (float*)d_out);
  }
}

// Round 4
// 225.420 us; speedup vs baseline: 1.1079x; 1.0036x over previous
//
#include <hip/hip_runtime.h>
#include <stdint.h>

#define NB 16
#define NQ 100
#define QP 112   // Q padded to 7*16 (rows 100..111 = ones rows; 111 used as mask-sum)
#define NG 16384
#define NT 50
#define TP 64    // T padded: 50..62 zero, 63 = ones column (gives Sum(m), Sum(sigmoid))
#define NL 21
#define CH 256   // K-chunk per block
#define NCHUNK (NG/CH)   // 64

// ws layout: ssp | dotm | dots   (all f32, zeroed each launch)
#define OFF_SSP  0u
#define SZ_SSP   (NB*QP*4u)                    // 7,168
#define OFF_DOTM (OFF_SSP + SZ_SSP)
#define SZ_DOT   ((size_t)NB*QP*TP*4u)         // 458,752
#define OFF_DOTS (OFF_DOTM + SZ_DOT)
#define ZERO_SZ  (OFF_DOTS + SZ_DOT)           // ~925 KB

typedef __bf16 bf16x8 __attribute__((ext_vector_type(8)));
typedef float f32x4 __attribute__((ext_vector_type(4)));
union Frag { uint32_t u[4]; bf16x8 v; };

__device__ __forceinline__ uint32_t pack_bf16(float a, float b) {
  uint32_t ua = __float_as_uint(a), ub = __float_as_uint(b);
  ua = (ua + 0x7FFFu + ((ua >> 16) & 1u)) >> 16;
  ub = (ub + 0x7FFFu + ((ub >> 16) & 1u)) & 0xFFFF0000u;
  return ua | ub;
}

// v_cvt_pk_bf16_f32: dst.lo16 = bf16(a), dst.hi16 = bf16(b)  (RNE)
__device__ __forceinline__ uint32_t cvtpk(float a, float b) {
  uint32_t r;
  asm("v_cvt_pk_bf16_f32 %0, %1, %2" : "=v"(r) : "v"(a), "v"(b));
  return r;
}

// ---------------------------------------------------------------------------
// fused main: per block (b, chunk): stage mask slice -> bf16 B-fragments in
// LDS (coalesced), then 7 waves (one 16-row q-tile each) run dual MFMA GEMM
// (m·maskT and sigmoid(m)·maskT) + softplus-log row sums. Atomic-accumulate.
// ---------------------------------------------------------------------------
__global__ __launch_bounds__(448, 7) void fused_main(
    const float* __restrict__ m, const float* __restrict__ mask,
    float* __restrict__ ssp, float* __restrict__ dotm,
    float* __restrict__ dots) {
  // B-fragment LDS: [ks 8][nt 4][lane 64][16B] = 32 KB
  __shared__ __align__(16) uint32_t bfr[8 * 4 * 64 * 4];
  int blk = blockIdx.x;
  int chunk = blk & (NCHUNK - 1), b = blk >> 6;
  int tid = threadIdx.x;

  // ---- stage: mask f32 -> bf16 fragments. thread (tb,sub): row t=tb,
  // floats k = sub*4 + i*32 (i=ks). Per instr: 8 subs cover 128B contiguous
  // of one row -> perfect coalescing. ds_write_b64 half-fragments.
  {
    int sub = tid & 7, tb = tid >> 3;            // tb 0..55
    uint2* U2 = (uint2*)bfr;
    int half = sub & 1;
    int lgs = sub >> 1;                          // lg of the staged halves
    for (int t = tb; t < 64; t += 56) {
      int nt = t >> 4;
      int l = lgs * 16 + (t & 15);
      if (t < NT) {
        const float* src = mask + ((size_t)(b*NT + t))*NG + chunk*CH + sub*4;
#pragma unroll
        for (int i = 0; i < 8; ++i) {
          float4 f = *(const float4*)(src + i*32);
          uint2 pk;
          pk.x = pack_bf16(f.x, f.y);
          pk.y = pack_bf16(f.z, f.w);
          U2[((i*4 + nt)*64 + l)*2 + half] = pk;
        }
      } else {
        uint32_t c = (t == 63) ? 0x3F803F80u : 0u;
        uint2 pk; pk.x = c; pk.y = c;
#pragma unroll
        for (int i = 0; i < 8; ++i)
          U2[((i*4 + nt)*64 + l)*2 + half] = pk;
      }
    }
  }
  __syncthreads();

  // ---- compute ----
  int lane = tid & 63, wv = tid >> 6;            // wv = q-tile 0..6
  int row16 = lane & 15, lg = lane >> 4;
  int q0 = wv * 16;
  int qrow = q0 + row16;
  bool pad = qrow > NQ - 1;                      // rows 100..111 -> ones rows
  int qc = pad ? NQ - 1 : qrow;
  const float* arow = m + (size_t)(b*NQ + qc)*NG + chunk*CH + lg*8;
  const bf16x8* BF = (const bf16x8*)bfr;

  f32x4 accm[4], accs[4];
#pragma unroll
  for (int nt = 0; nt < 4; ++nt) { accm[nt] = (f32x4)(0.f); accs[nt] = (f32x4)(0.f); }
  float sl = 0.f;                                // sum log2(1+e^-x)

#pragma unroll 2
  for (int ks = 0; ks < 8; ++ks) {
    const float4* p = (const float4*)(arow + ks*32);
    float4 v0 = p[0], v1 = p[1];
    float av[8] = {v0.x, v0.y, v0.z, v0.w, v1.x, v1.y, v1.z, v1.w};
    Frag mf, sf;
#pragma unroll
    for (int j = 0; j < 8; j += 2) {
      float x0 = av[j], x1 = av[j+1];
      x0 = pad ? 1.f : x0;                       // exact ones row
      x1 = pad ? 1.f : x1;
      float e0 = __builtin_amdgcn_exp2f(x0 * -1.442695041f);
      float e1 = __builtin_amdgcn_exp2f(x1 * -1.442695041f);
      float u0 = 1.f + e0, u1 = 1.f + e1;
      float r0 = __builtin_amdgcn_rcpf(u0), r1 = __builtin_amdgcn_rcpf(u1);
      sl += __builtin_amdgcn_logf(u0) + __builtin_amdgcn_logf(u1);
      mf.u[j >> 1] = cvtpk(x0, x1);
      sf.u[j >> 1] = cvtpk(r0, r1);
    }
#pragma unroll
    for (int nt = 0; nt < 4; ++nt) {
      bf16x8 bb = BF[(ks*4 + nt)*64 + lane];     // linear -> conflict-free
      accm[nt] = __builtin_amdgcn_mfma_f32_16x16x32_bf16(mf.v, bb, accm[nt], 0, 0, 0);
      accs[nt] = __builtin_amdgcn_mfma_f32_16x16x32_bf16(sf.v, bb, accs[nt], 0, 0, 0);
    }
  }

  // softplus-log row sums: lanes {l, l^16, l^32, l^48} share a q-row
  sl += __shfl_xor(sl, 16); sl += __shfl_xor(sl, 32);
  if (lg == 0) atomicAdd(&ssp[b*QP + q0 + row16], sl);

  // C/D layout: col = lane&15 (t), row = (lane>>4)*4 + r (q offset)
#pragma unroll
  for (int nt = 0; nt < 4; ++nt) {
    int t = nt*16 + row16;
#pragma unroll
    for (int r = 0; r < 4; ++r) {
      int qq = q0 + lg*4 + r;
      atomicAdd(&dotm[(size_t)(b*QP + qq)*TP + t], accm[nt][r]);
      atomicAdd(&dots[(size_t)(b*QP + qq)*TP + t], accs[nt][r]);
    }
  }
}

// ---- finalize: class softmax + assemble output ----
__global__ __launch_bounds__(64) void finalize_k(
    const float* __restrict__ cls, const int* __restrict__ labels,
    const float* __restrict__ ssp, const float* __restrict__ dotm,
    const float* __restrict__ dots, float* __restrict__ out) {
  int blk = blockIdx.x;
  int b = blk / NQ, q = blk % NQ;
  int lane = threadIdx.x;
  const float* lgt = cls + (size_t)(b*NQ + q) * NL;
  float v = (lane < NL) ? lgt[lane] : -1e30f;
  float mx = v;
  for (int s = 32; s; s >>= 1) mx = fmaxf(mx, __shfl_xor(mx, s));
  float e = (lane < NL) ? __expf(v - mx) : 0.f;
  float se = e;
  for (int s = 32; s; s >>= 1) se += __shfl_xor(se, s);

  if (lane < NT) {
    int lbl = labels[b*NT + lane];
    float p = __expf(lgt[lbl] - mx) / se;        // softmax prob at label
    size_t base = (size_t)(b*QP + q) * TP;
    float s1 = dotm[base + 63] + 0.69314718056f * ssp[b*QP + q]; // Sum softplus
    float sg = dots[base + 63];                                  // Sum sigmoid
    float msum = dotm[(size_t)(b*QP + 111)*TP + lane];           // Sum mask (ones row)
    float dm = dotm[base + lane];
    float ds = dots[base + lane];
    float cmask = (s1 - dm) * (1.f / (float)NG);
    float cdice = 1.f - (2.f*ds + 1.f) / (sg + msum + 1.f);
    out[(size_t)(b*NQ + q)*NT + lane] = cmask - p + cdice;
  }
}

// ============================================================================
extern "C" void kernel_launch(void* const* d_in, const int* in_sizes, int n_in,
                              void* d_out, int out_size, void* d_ws, size_t ws_size,
                              hipStream_t stream) {
  const float* mq = (const float*)d_in[0];   // [16,100,16384]
  const float* cq = (const float*)d_in[1];   // [16,100,21]
  const float* ml = (const float*)d_in[2];   // [16,50,16384]
  const int*   cl = (const int*)d_in[3];     // [16,50]
  char* ws = (char*)d_ws;
  float* ssp  = (float*)(ws + OFF_SSP);
  float* dotm = (float*)(ws + OFF_DOTM);
  float* dots = (float*)(ws + OFF_DOTS);

  hipMemsetAsync(ws, 0, ZERO_SZ, stream);
  fused_main<<<NB*NCHUNK, 448, 0, stream>>>(mq, ml, ssp, dotm, dots);
  finalize_k<<<NB*NQ, 64, 0, stream>>>(cq, cl, ssp, dotm, dots, (float*)d_out);
}

// Round 5
// 220.616 us; speedup vs baseline: 1.1320x; 1.0218x over previous
//
#include <hip/hip_runtime.h>
#include <stdint.h>

#define NB 16
#define NQ 100
#define QP 112   // Q padded to 7*16; rows 100..110 dummy-ones, row 111 = mask-sum row
#define NG 16384
#define NT 50
#define TP 64    // T padded: 50..62 zero, 63 = ones column (Sum(m), Sum(sigmoid))
#define NL 21
#define NCH 32   // K-split chunks; K per block = 512
#define CH 512

// ws layout (bytes)
#define SZ_P     ((size_t)NCH*NB*7*1024*4)     // 14,680,064 per partial array
#define OFF_PM   0u
#define OFF_PS   (SZ_P)
#define OFF_RM   (2*SZ_P)                      // reduced [b][wv][1024]
#define SZ_R     ((size_t)NB*7*1024*4)         // 458,752
#define OFF_RS   (OFF_RM + SZ_R)
#define OFF_SSP  (OFF_RS + SZ_R)
#define SZ_SSP   (NB*QP*4u)                    // 7,168
#define NEED_WS  (OFF_SSP + SZ_SSP)            // ~30.3 MB (harness ws ≈ 400 MB)

typedef __bf16 bf16x8 __attribute__((ext_vector_type(8)));
typedef float f32x4 __attribute__((ext_vector_type(4)));
union Frag { uint32_t u[4]; bf16x8 v; };

__device__ __forceinline__ uint32_t pack_bf16(float a, float b) {
  uint32_t ua = __float_as_uint(a), ub = __float_as_uint(b);
  ua = (ua + 0x7FFFu + ((ua >> 16) & 1u)) >> 16;
  ub = (ub + 0x7FFFu + ((ub >> 16) & 1u)) & 0xFFFF0000u;
  return ua | ub;
}

// ---------------------------------------------------------------------------
// kernel1: per block (b, chunk of K=512): stage mask slice -> bf16 MFMA
// B-fragments in LDS (one barrier), 7 waves (16 q-rows each) run dual GEMM
// (m·maskT, sigmoid(m)·maskT) + softplus-log row sums. Partials STREAMED to
// global (no atomics): pdm/pds[((b*32+ch)*7+wv)*1024 + lane*16 + nt*4 + r].
// ---------------------------------------------------------------------------
__global__ __launch_bounds__(448) void gemm_part(
    const float* __restrict__ m, const float* __restrict__ mask,
    float* __restrict__ ssp, float* __restrict__ pdm,
    float* __restrict__ pds) {
  __shared__ __align__(16) uint32_t bfr[16 * 4 * 64 * 4];   // 64 KB
  int blk = blockIdx.x;
  int chunk = blk & (NCH - 1), b = blk >> 5;
  int tid = threadIdx.x;

  // ---- stage: 16 threads per t-row; 16 thr x 16B = 256B contiguous loads
  {
    int sub = tid & 15, tb = tid >> 4;           // tb 0..27
    uint2* U2 = (uint2*)bfr;
    int lgs = (sub & 7) >> 1, half = sub & 1;
    for (int t = tb; t < 64; t += 28) {
      int nt = t >> 4;
      if (t < NT) {
        const float* src = mask + ((size_t)(b*NT + t))*NG + chunk*CH + sub*4;
#pragma unroll
        for (int i = 0; i < 8; ++i) {
          float4 f = *(const float4*)(src + i*64);
          int ks = (sub >> 3) + i*2;
          uint2 pk; pk.x = pack_bf16(f.x, f.y); pk.y = pack_bf16(f.z, f.w);
          U2[((ks*4 + nt)*64 + lgs*16 + (t & 15))*2 + half] = pk;
        }
      } else {
        uint32_t c = (t == 63) ? 0x3F803F80u : 0u;
        uint2 pk; pk.x = c; pk.y = c;
#pragma unroll
        for (int i = 0; i < 8; ++i) {
          int ks = (sub >> 3) + i*2;
          U2[((ks*4 + nt)*64 + lgs*16 + (t & 15))*2 + half] = pk;
        }
      }
    }
  }
  __syncthreads();

  // ---- compute ----
  int lane = tid & 63, wv = tid >> 6;            // wv = q-tile 0..6
  int row16 = lane & 15, lg = lane >> 4;
  int q0 = wv * 16;
  int qrow = q0 + row16;
  bool pad = qrow > NQ - 1;                      // rows 100..111 -> ones rows
  int qc = pad ? NQ - 1 : qrow;
  const float* arow = m + (size_t)(b*NQ + qc)*NG + chunk*CH + lg*8;
  const bf16x8* BF = (const bf16x8*)bfr;

  f32x4 accm[4], accs[4];
#pragma unroll
  for (int nt = 0; nt < 4; ++nt) { accm[nt] = (f32x4)(0.f); accs[nt] = (f32x4)(0.f); }
  float sl = 0.f;                                // sum log2(1+e^-x)

#pragma unroll 2
  for (int ks = 0; ks < 16; ++ks) {
    const float4* p = (const float4*)(arow + ks*32);
    float4 v0 = p[0], v1 = p[1];
    float av[8] = {v0.x, v0.y, v0.z, v0.w, v1.x, v1.y, v1.z, v1.w};
    Frag mf, sf;
#pragma unroll
    for (int j = 0; j < 8; j += 2) {
      float x0 = av[j], x1 = av[j+1];
      x0 = pad ? 1.f : x0;
      x1 = pad ? 1.f : x1;
      float e0 = __builtin_amdgcn_exp2f(x0 * -1.442695041f);
      float e1 = __builtin_amdgcn_exp2f(x1 * -1.442695041f);
      float u0 = 1.f + e0, u1 = 1.f + e1;
      float r0 = __builtin_amdgcn_rcpf(u0), r1 = __builtin_amdgcn_rcpf(u1);
      sl += __builtin_amdgcn_logf(u0) + __builtin_amdgcn_logf(u1);
      mf.u[j >> 1] = pack_bf16(x0, x1);
      sf.u[j >> 1] = pack_bf16(r0, r1);
    }
#pragma unroll
    for (int nt = 0; nt < 4; ++nt) {
      bf16x8 bb = BF[(ks*4 + nt)*64 + lane];     // linear -> conflict-free
      accm[nt] = __builtin_amdgcn_mfma_f32_16x16x32_bf16(mf.v, bb, accm[nt], 0, 0, 0);
      accs[nt] = __builtin_amdgcn_mfma_f32_16x16x32_bf16(sf.v, bb, accs[nt], 0, 0, 0);
    }
  }

  // softplus-log row sums: lanes {l, l^16, l^32, l^48} share a q-row
  sl += __shfl_xor(sl, 16); sl += __shfl_xor(sl, 32);
  if (lg == 0) atomicAdd(&ssp[b*QP + q0 + row16], sl);

  // streamed partial store, fragment-native order (16 f32/lane, coalesced)
  size_t base = ((size_t)(b*NCH + chunk)*7 + wv)*1024 + lane*16;
#pragma unroll
  for (int nt = 0; nt < 4; ++nt) {
    *(f32x4*)(pdm + base + nt*4) = accm[nt];
    *(f32x4*)(pds + base + nt*4) = accs[nt];
  }
}

// ---------------------------------------------------------------------------
// kernel2: reduce partials over 32 chunks (coalesced both sides)
// ---------------------------------------------------------------------------
__global__ __launch_bounds__(256) void reduce_k(
    const float* __restrict__ pdm, const float* __restrict__ pds,
    float* __restrict__ rm, float* __restrict__ rs) {
  int idx = blockIdx.x*256 + threadIdx.x;        // 114,688 total = 448 blocks
  int b = idx / 7168, rem = idx % 7168;
  size_t bp = (size_t)b*NCH*7168 + rem;
  float sm = 0.f, ss = 0.f;
#pragma unroll
  for (int ch = 0; ch < NCH; ++ch) {
    sm += pdm[bp + (size_t)ch*7168];
    ss += pds[bp + (size_t)ch*7168];
  }
  rm[idx] = sm;
  rs[idx] = ss;
}

// ---------------------------------------------------------------------------
// kernel3: class softmax + assemble output
// reduced arrays are in fragment order: elem(q,t) at
//   (b*7 + q>>4)*1024 + (((q&15)>>2)*16 + (t&15))*16 + (t>>4)*4 + (q&3)
// ---------------------------------------------------------------------------
__device__ __forceinline__ size_t ridx(int b, int q, int t) {
  return (size_t)(b*7 + (q >> 4))*1024
       + (size_t)((((q & 15) >> 2)*16 + (t & 15))*16 + (t >> 4)*4 + (q & 3));
}

__global__ __launch_bounds__(64) void finalize_k(
    const float* __restrict__ cls, const int* __restrict__ labels,
    const float* __restrict__ ssp, const float* __restrict__ rm,
    const float* __restrict__ rs, float* __restrict__ out) {
  int blk = blockIdx.x;
  int b = blk / NQ, q = blk % NQ;
  int lane = threadIdx.x;
  const float* lgt = cls + (size_t)(b*NQ + q) * NL;
  float v = (lane < NL) ? lgt[lane] : -1e30f;
  float mx = v;
  for (int s = 32; s; s >>= 1) mx = fmaxf(mx, __shfl_xor(mx, s));
  float e = (lane < NL) ? __expf(v - mx) : 0.f;
  float se = e;
  for (int s = 32; s; s >>= 1) se += __shfl_xor(se, s);

  if (lane < NT) {
    int lbl = labels[b*NT + lane];
    float p = __expf(lgt[lbl] - mx) / se;               // softmax prob at label
    // Sum softplus(m) = Sum m (ones col) + ln2 * Sum log2(1+e^-m)
    float s1 = rm[ridx(b, q, 63)] + 0.69314718056f * ssp[b*QP + q];
    float sg = rs[ridx(b, q, 63)];                      // Sum sigmoid
    float msum = rm[ridx(b, 111, lane)];                // Sum mask (ones row)
    float dm = rm[ridx(b, q, lane)];
    float ds = rs[ridx(b, q, lane)];
    float cmask = (s1 - dm) * (1.f / (float)NG);
    float cdice = 1.f - (2.f*ds + 1.f) / (sg + msum + 1.f);
    out[(size_t)(b*NQ + q)*NT + lane] = cmask - p + cdice;
  }
}

// ============================================================================
extern "C" void kernel_launch(void* const* d_in, const int* in_sizes, int n_in,
                              void* d_out, int out_size, void* d_ws, size_t ws_size,
                              hipStream_t stream) {
  const float* mq = (const float*)d_in[0];   // [16,100,16384]
  const float* cq = (const float*)d_in[1];   // [16,100,21]
  const float* ml = (const float*)d_in[2];   // [16,50,16384]
  const int*   cl = (const int*)d_in[3];     // [16,50]
  char* ws = (char*)d_ws;
  float* pdm = (float*)(ws + OFF_PM);
  float* pds = (float*)(ws + OFF_PS);
  float* rm  = (float*)(ws + OFF_RM);
  float* rs  = (float*)(ws + OFF_RS);
  float* ssp = (float*)(ws + OFF_SSP);

  hipMemsetAsync(ssp, 0, SZ_SSP, stream);
  gemm_part<<<NB*NCH, 448, 0, stream>>>(mq, ml, ssp, pdm, pds);
  reduce_k<<<448, 256, 0, stream>>>(pdm, pds, rm, rs);
  finalize_k<<<NB*NQ, 64, 0, stream>>>(cq, cl, ssp, rm, rs, (float*)d_out);
}